// Round 2
// baseline (4910.102 us; speedup 1.0000x reference)
//
#include <hip/hip_runtime.h>
#include <hip/hip_bf16.h>
#include <stdint.h>

#define T_STEPS 200
#define BATCH   256
#define NS      256   // states S
#define NA      16    // actions A
#define DOBS    128
#define DCTL    16
#define LOG2PI  1.8378770664093453f
#define EPS_F   1e-6f

typedef float f32x4 __attribute__((ext_vector_type(4)));
typedef short s16x8 __attribute__((ext_vector_type(8)));
typedef short s16x4 __attribute__((ext_vector_type(4)));

static __device__ __forceinline__ unsigned short f2bf(float f) {
    union { float f; unsigned u; } v; v.f = f;
    unsigned u = v.u;
    u += 0x7fffu + ((u >> 16) & 1u);   // RNE
    return (unsigned short)(u >> 16);
}

// ---- prep: obs weights  W=(-0.5*iv || mu*iv) stored transposed [256 d'][256 s], C[s]
__global__ __launch_bounds__(128) void k_prep_obs(const float* __restrict__ obs_mu,
                                                  const float* __restrict__ obs_lv,
                                                  float* __restrict__ WT,
                                                  float* __restrict__ Cs) {
    int s = blockIdx.x, d = threadIdx.x;
    float lv = obs_lv[s * DOBS + d];
    float mu = obs_mu[s * DOBS + d];
    float iv = expf(-lv);
    WT[d * NS + s]          = -0.5f * iv;
    WT[(DOBS + d) * NS + s] = mu * iv;
    float part = mu * mu * iv + lv;
    for (int m = 1; m < 64; m <<= 1) part += __shfl_xor(part, m, 64);
    __shared__ float red[2];
    if ((threadIdx.x & 63) == 0) red[threadIdx.x >> 6] = part;
    __syncthreads();
    if (threadIdx.x == 0) Cs[s] = -0.5f * (red[0] + red[1] + DOBS * LOG2PI);
}

// ---- prep: ctl weights
__global__ __launch_bounds__(256) void k_prep_ctl(const float* __restrict__ cmu,
                                                  const float* __restrict__ clv,
                                                  float* __restrict__ cw1,
                                                  float* __restrict__ cw2,
                                                  float* __restrict__ cc) {
    int t = threadIdx.x;           // (a,d) pairs: a = t>>4, d = t&15
    int a = t >> 4, d = t & 15;
    float lv = clv[a * DCTL + d];
    float mu = cmu[a * DCTL + d];
    float iv = expf(-lv);
    cw1[t] = -0.5f * iv;
    cw2[t] = mu * iv;
    float part = mu * mu * iv + lv;
    for (int m = 1; m < 16; m <<= 1) part += __shfl_xor(part, m, 64);
    if (d == 0) cc[a] = -0.5f * (part + DCTL * LOG2PI);
}

// ---- prep: log_softmax(pi0)
__global__ __launch_bounds__(64) void k_prep_pi0(const float* __restrict__ pl,
                                                 float* __restrict__ lpi0) {
    int l = threadIdx.x;
    float v[4]; float m = -1e30f;
    for (int k = 0; k < 4; k++) { v[k] = pl[l + 64 * k]; m = fmaxf(m, v[k]); }
    for (int mm = 1; mm < 64; mm <<= 1) m = fmaxf(m, __shfl_xor(m, mm, 64));
    float ssum = 0.f;
    for (int k = 0; k < 4; k++) ssum += expf(v[k] - m);
    for (int mm = 1; mm < 64; mm <<= 1) ssum += __shfl_xor(ssum, mm, 64);
    float ls = logf(ssum);
    for (int k = 0; k < 4; k++) lpi0[l + 64 * k] = v[k] - m - ls;
}

// ---- prep: trans softmax, scattered into bf16 MFMA B-fragment layout.
// Column c = j*16 + a (4096 cols). Frag layout: TRf[ct=j][kk=i>>5][lane][e=i&7],
// lane = ((i>>3)&3)*16 + a  (B: col=lane&15, k-slot=(lane>>4)*8+e).
__global__ __launch_bounds__(256) void k_trans(const float* __restrict__ tl,
                                               __hip_bfloat16* __restrict__ TRf) {
    int wave = threadIdx.x >> 6, lane = threadIdx.x & 63;
    int row = blockIdx.x * 4 + wave;        // (a,i) row in [0,4096)
    int a = row >> 8, i = row & 255;
    const float* src = tl + (size_t)row * NS;
    float v[4]; float m = -1e30f;
    for (int k = 0; k < 4; k++) { v[k] = src[lane + 64 * k]; m = fmaxf(m, v[k]); }
    for (int mm = 1; mm < 64; mm <<= 1) m = fmaxf(m, __shfl_xor(m, mm, 64));
    float ssum = 0.f; float ev[4];
    for (int k = 0; k < 4; k++) { ev[k] = expf(v[k] - m); ssum += ev[k]; }
    for (int mm = 1; mm < 64; mm <<= 1) ssum += __shfl_xor(ssum, mm, 64);
    float inv = 1.f / ssum;
    int kk = i >> 5;
    int lsub = ((i >> 3) & 3) * 16 + a;
    int e = i & 7;
    for (int k = 0; k < 4; k++) {
        int j = lane + 64 * k;
        float p = ev[k] * inv;
        TRf[((size_t)(j * 8 + kk) * 64 + lsub) * 8 + e] = __float2bfloat16(p);
    }
}

// ---- prep: act_prior into B-frag layout, split bf16 hi/lo for precision.
// APf[kk][lane][e] = act_prior[i][a], i = kk*32 + (lane>>4)*8 + e, a = lane&15.
__global__ __launch_bounds__(64) void k_prep_ap(const float* __restrict__ ap,
                                                __hip_bfloat16* __restrict__ APh,
                                                __hip_bfloat16* __restrict__ APl) {
    int kk = blockIdx.x, lane = threadIdx.x;
    for (int e = 0; e < 8; e++) {
        int i = kk * 32 + (lane >> 4) * 8 + e;
        int a = lane & 15;
        float v = ap[i * NA + a];
        __hip_bfloat16 hb = __float2bfloat16(v);
        float hi = __bfloat162float(hb);
        APh[(kk * 64 + lane) * 8 + e] = hb;
        APl[(kk * 64 + lane) * 8 + e] = __float2bfloat16(v - hi);
    }
}

// ---- obs_lp for all (t,b): GEMM [51200,256]x[256,256] f32. Block = 32 rows.
__global__ __launch_bounds__(256) void k_obslp(const float* __restrict__ x,
                                               const float* __restrict__ WT,
                                               const float* __restrict__ Cs,
                                               float* __restrict__ obs) {
    __shared__ float f[32 * 256];
    int r0 = blockIdx.x * 32;
    for (int idx = threadIdx.x; idx < 32 * DOBS; idx += 256) {
        int r = idx >> 7, d = idx & 127;
        float v = x[(size_t)(r0 + r) * DOBS + d];
        f[r * 256 + d] = v * v;
        f[r * 256 + 128 + d] = v;
    }
    __syncthreads();
    int s = threadIdx.x;
    float acc[32];
#pragma unroll
    for (int r = 0; r < 32; r++) acc[r] = 0.f;
    for (int d4 = 0; d4 < 64; d4++) {
        float w0 = WT[(d4 * 4 + 0) * NS + s];
        float w1 = WT[(d4 * 4 + 1) * NS + s];
        float w2 = WT[(d4 * 4 + 2) * NS + s];
        float w3 = WT[(d4 * 4 + 3) * NS + s];
#pragma unroll
        for (int r = 0; r < 32; r++) {
            f32x4 fv = *reinterpret_cast<const f32x4*>(&f[r * 256 + d4 * 4]);
            acc[r] += fv.x * w0 + fv.y * w1 + fv.z * w2 + fv.w * w3;
        }
    }
    float c = Cs[s];
#pragma unroll
    for (int r = 0; r < 32; r++) obs[(size_t)(r0 + r) * NS + s] = acc[r] + c;
}

// ---- ctl_lp for all (s,b,a), s in [0,199)
__global__ __launch_bounds__(256) void k_ctllp(const float* __restrict__ u,
                                               const float* __restrict__ cw1,
                                               const float* __restrict__ cw2,
                                               const float* __restrict__ cc,
                                               float* __restrict__ ctl) {
    int idx = blockIdx.x * 256 + threadIdx.x;   // (r, a)
    int r = idx >> 4, a = idx & 15;
    const float* ur = u + (size_t)r * DCTL;
    const float* w1 = cw1 + a * DCTL;
    const float* w2 = cw2 + a * DCTL;
    float acc = cc[a];
#pragma unroll
    for (int d = 0; d < 16; d++) {
        float uv = ur[d];
        acc += uv * uv * w1[d] + uv * w2[d];
    }
    ctl[idx] = acc;
}

// ================= persistent scan kernel =================
// grid = 256 blocks (1/CU), 256 threads. 16 bt-groups x 16 jt.
// XCD-swizzle: bt-group's 16 blocks co-located on one XCD (perf heuristic only;
// correctness via agent-scope atomics/fences).
struct ScanArgs {
    const float* obs;
    const float* ctlp;
    const float* lpi0;
    const __hip_bfloat16* TRf;
    const __hip_bfloat16* APh;
    const __hip_bfloat16* APl;
    float* lgA;
    float* lgB;
    float* out_ab;
    float* out_aa;
    int*   flags;     // one counter per bt, 32-int stride
};

__global__ __launch_bounds__(256, 1) void k_scan_p(ScanArgs A) {
    const int bid  = blockIdx.x;
    const int bt   = (bid & 7) * 2 + ((bid >> 3) >> 4);  // same-XCD groups of 16
    const int jt   = (bid >> 3) & 15;
    const int tid  = threadIdx.x;
    const int wv   = tid >> 6, lane = tid & 63;
    const int kgrp = lane >> 4, arow = lane & 15;
    const int b0   = bt * 16;
    int* flag = A.flags + bt * 32;

    __shared__ short AFL[8][16][32];   // bf16 p in A-frag layout [kk][row][koff]

    // ---- preload constant fragments into registers (1 block/CU -> VGPRs free)
    s16x8 bfr[4][8];
#pragma unroll
    for (int q = 0; q < 4; q++) {
        int ct = jt * 16 + wv * 4 + q;
#pragma unroll
        for (int kk = 0; kk < 8; kk++)
            bfr[q][kk] = *((const s16x8*)A.TRf + (size_t)(ct * 8 + kk) * 64 + lane);
    }
    s16x8 aph[8], apl[8];
#pragma unroll
    for (int kk = 0; kk < 8; kk++) {
        aph[kk] = *((const s16x8*)A.APh + kk * 64 + lane);
        apl[kk] = *((const s16x8*)A.APl + kk * 64 + lane);
    }
    f32x4 lp0 = *(const f32x4*)&A.lpi0[lane * 4];

    for (int s = 0; s < T_STEPS - 1; s++) {
        const float* lin = (s & 1) ? A.lgB : A.lgA;   // R(s) = buf[s&1]
        float*       lout = (s & 1) ? A.lgA : A.lgB;  // W(s) = buf[(s+1)&1]

        // obs prefetch for time s+1 (consumed at end of phase 5)
        float obs_pf[16];
#pragma unroll
        for (int q2 = 0; q2 < 4; q2++)
#pragma unroll
            for (int r = 0; r < 4; r++)
                obs_pf[q2 * 4 + r] =
                    A.obs[((size_t)(s + 1) * BATCH + b0 + kgrp * 4 + r) * NS + jt * 16 + wv * 4 + q2];

        // ---- wait for bt-group to finish step s-1
        if (s > 0) {
            if (tid == 0) {
                int tgt = 16 * s;
                while (__hip_atomic_load(flag, __ATOMIC_ACQUIRE, __HIP_MEMORY_SCOPE_AGENT) < tgt)
                    __builtin_amdgcn_s_sleep(2);
            }
            __syncthreads();
        }

        // ---- phase 1: softmax beliefs, write alpha_b[s] (jt-partitioned) + AFL
#pragma unroll
        for (int q = 0; q < 4; q++) {
            int r = wv * 4 + q, bb = b0 + r;
            f32x4 v;
            if (s == 0) {
                f32x4 o = *(const f32x4*)&A.obs[(size_t)bb * NS + lane * 4];
                v = o + lp0;
            } else {
                v = *(const f32x4*)&lin[(size_t)bb * NS + lane * 4];
            }
            float m = fmaxf(fmaxf(v.x, v.y), fmaxf(v.z, v.w));
            for (int mm = 1; mm < 64; mm <<= 1) m = fmaxf(m, __shfl_xor(m, mm, 64));
            f32x4 e;
            e.x = __expf(v.x - m); e.y = __expf(v.y - m);
            e.z = __expf(v.z - m); e.w = __expf(v.w - m);
            float ss = (e.x + e.y) + (e.z + e.w);
            for (int mm = 1; mm < 64; mm <<= 1) ss += __shfl_xor(ss, mm, 64);
            float inv = 1.f / ss;
            f32x4 p = e * inv;
            if ((lane >> 2) == jt)
                *(f32x4*)&A.out_ab[((size_t)s * BATCH + bb) * NS + lane * 4] = p;
            s16x4 sv;
            sv[0] = (short)f2bf(p.x); sv[1] = (short)f2bf(p.y);
            sv[2] = (short)f2bf(p.z); sv[3] = (short)f2bf(p.w);
            *(s16x4*)&AFL[lane >> 3][r][(lane & 7) * 4] = sv;   // kk=lane>>3, koff=(lane&7)*4
        }
        __syncthreads();

        // ---- A-fragments for this bt's 16 rows
        s16x8 afr[8];
#pragma unroll
        for (int kk = 0; kk < 8; kk++)
            afr[kk] = *(const s16x8*)&AFL[kk][arow][kgrp * 8];

        // ---- phase 3: g = p @ act_prior via MFMA (hi+lo), then a_t in-register.
        // g[q] = g[row=kgrp*4+q][a=arow]  (C/D: col=lane&15, row=(lane>>4)*4+reg)
        f32x4 g = {0.f, 0.f, 0.f, 0.f};
#pragma unroll
        for (int kk = 0; kk < 8; kk++)
            g = __builtin_amdgcn_mfma_f32_16x16x32_bf16(afr[kk], aph[kk], g, 0, 0, 0);
#pragma unroll
        for (int kk = 0; kk < 8; kk++)
            g = __builtin_amdgcn_mfma_f32_16x16x32_bf16(afr[kk], apl[kk], g, 0, 0, 0);

        float at[4];
#pragma unroll
        for (int q = 0; q < 4; q++) {
            float gv = g[q];
            float m = gv;
            for (int mm = 1; mm < 16; mm <<= 1) m = fmaxf(m, __shfl_xor(m, mm, 64));
            float e1 = __expf(gv - m);
            float s1 = e1;
            for (int mm = 1; mm < 16; mm <<= 1) s1 += __shfl_xor(s1, mm, 64);
            float apr = e1 / s1;
            float al = A.ctlp[((size_t)s * BATCH + b0 + kgrp * 4 + q) * NA + arow]
                       + __logf(apr + EPS_F);
            float m2 = al;
            for (int mm = 1; mm < 16; mm <<= 1) m2 = fmaxf(m2, __shfl_xor(m2, mm, 64));
            float e2 = __expf(al - m2);
            float s2 = e2;
            for (int mm = 1; mm < 16; mm <<= 1) s2 += __shfl_xor(s2, mm, 64);
            at[q] = e2 / s2;
            if (jt == 0)
                A.out_aa[((size_t)s * BATCH + b0 + kgrp * 4 + q) * NA + arow] = at[q];
        }

        // ---- phase 5: m2 = p @ trans (per col-tile), contract a_t, write logits
#pragma unroll
        for (int q2 = 0; q2 < 4; q2++) {
            int ct = jt * 16 + wv * 4 + q2;
            f32x4 acc = {0.f, 0.f, 0.f, 0.f};
#pragma unroll
            for (int kk = 0; kk < 8; kk++)
                acc = __builtin_amdgcn_mfma_f32_16x16x32_bf16(afr[kk], bfr[q2][kk], acc, 0, 0, 0);
#pragma unroll
            for (int r = 0; r < 4; r++) {
                float vv = acc[r] * at[r];
                for (int mm = 1; mm < 16; mm <<= 1) vv += __shfl_xor(vv, mm, 64);
                if (arow == 0) {
                    float lz = __logf(vv + NS * EPS_F);
                    lout[(size_t)(b0 + kgrp * 4 + r) * NS + ct] = obs_pf[q2 * 4 + r] + lz;
                }
            }
        }

        // ---- signal step complete (barrier drains all waves' stores first)
        __syncthreads();
        if (tid == 0) {
            __threadfence();
            __hip_atomic_fetch_add(flag, 1, __ATOMIC_RELEASE, __HIP_MEMORY_SCOPE_AGENT);
        }
    }

    // ---- epilogue: softmax of final beliefs -> alpha_b[T-1]
    if (tid == 0) {
        int tgt = 16 * (T_STEPS - 1);
        while (__hip_atomic_load(flag, __ATOMIC_ACQUIRE, __HIP_MEMORY_SCOPE_AGENT) < tgt)
            __builtin_amdgcn_s_sleep(2);
    }
    __syncthreads();
    const float* lin = ((T_STEPS - 1) & 1) ? A.lgB : A.lgA;
#pragma unroll
    for (int q = 0; q < 4; q++) {
        int r = wv * 4 + q, bb = b0 + r;
        f32x4 v = *(const f32x4*)&lin[(size_t)bb * NS + lane * 4];
        float m = fmaxf(fmaxf(v.x, v.y), fmaxf(v.z, v.w));
        for (int mm = 1; mm < 64; mm <<= 1) m = fmaxf(m, __shfl_xor(m, mm, 64));
        f32x4 e;
        e.x = __expf(v.x - m); e.y = __expf(v.y - m);
        e.z = __expf(v.z - m); e.w = __expf(v.w - m);
        float ss = (e.x + e.y) + (e.z + e.w);
        for (int mm = 1; mm < 64; mm <<= 1) ss += __shfl_xor(ss, mm, 64);
        float inv = 1.f / ss;
        f32x4 p = e * inv;
        if ((lane >> 2) == jt)
            *(f32x4*)&A.out_ab[((size_t)(T_STEPS - 1) * BATCH + bb) * NS + lane * 4] = p;
    }
}

extern "C" void kernel_launch(void* const* d_in, const int* in_sizes, int n_in,
                              void* d_out, int out_size, void* d_ws, size_t ws_size,
                              hipStream_t stream) {
    const float* x            = (const float*)d_in[0];
    const float* u            = (const float*)d_in[1];
    const float* obs_mu       = (const float*)d_in[2];
    const float* obs_lv       = (const float*)d_in[3];
    const float* ctl_mu       = (const float*)d_in[4];
    const float* ctl_lv       = (const float*)d_in[5];
    const float* trans_logits = (const float*)d_in[6];
    const float* pi0_logits   = (const float*)d_in[7];
    const float* act_prior    = (const float*)d_in[8];

    float* out_ab = (float*)d_out;
    float* out_aa = out_ab + (size_t)T_STEPS * BATCH * NS;

    char* w = (char*)d_ws;
    size_t off = 0;
    auto alloc = [&](size_t bytes) -> void* {
        void* pp = w + off;
        off += (bytes + 255) & ~(size_t)255;
        return pp;
    };
    float* WT   = (float*)alloc((size_t)256 * 256 * 4);
    float* Cs   = (float*)alloc(256 * 4);
    float* cw1  = (float*)alloc(256 * 4);
    float* cw2  = (float*)alloc(256 * 4);
    float* cc   = (float*)alloc(16 * 4);
    float* lpi0 = (float*)alloc(256 * 4);
    __hip_bfloat16* TRf = (__hip_bfloat16*)alloc((size_t)4096 * 256 * 2);
    __hip_bfloat16* APh = (__hip_bfloat16*)alloc((size_t)8 * 64 * 8 * 2);
    __hip_bfloat16* APl = (__hip_bfloat16*)alloc((size_t)8 * 64 * 8 * 2);
    float* obs  = (float*)alloc((size_t)T_STEPS * BATCH * NS * 4);
    float* ctlp = (float*)alloc((size_t)(T_STEPS - 1) * BATCH * NA * 4);
    float* lgA  = (float*)alloc((size_t)BATCH * NS * 4);
    float* lgB  = (float*)alloc((size_t)BATCH * NS * 4);
    int*   flags = (int*)alloc(16 * 32 * 4);
    if (off > ws_size) return;   // insufficient scratch -> fail loudly

    k_prep_obs<<<256, 128, 0, stream>>>(obs_mu, obs_lv, WT, Cs);
    k_prep_ctl<<<1, 256, 0, stream>>>(ctl_mu, ctl_lv, cw1, cw2, cc);
    k_prep_pi0<<<1, 64, 0, stream>>>(pi0_logits, lpi0);
    k_trans<<<1024, 256, 0, stream>>>(trans_logits, TRf);
    k_prep_ap<<<8, 64, 0, stream>>>(act_prior, APh, APl);
    k_obslp<<<1600, 256, 0, stream>>>(x, WT, Cs, obs);
    k_ctllp<<<3184, 256, 0, stream>>>(u, cw1, cw2, cc, ctlp);
    hipMemsetAsync(flags, 0, 16 * 32 * 4, stream);

    ScanArgs args;
    args.obs = obs; args.ctlp = ctlp; args.lpi0 = lpi0;
    args.TRf = TRf; args.APh = APh; args.APl = APl;
    args.lgA = lgA; args.lgB = lgB;
    args.out_ab = out_ab; args.out_aa = out_aa; args.flags = flags;
    k_scan_p<<<256, 256, 0, stream>>>(args);
}

// Round 3
// 2320.262 us; speedup vs baseline: 2.1162x; 2.1162x over previous
//
#include <hip/hip_runtime.h>
#include <hip/hip_bf16.h>
#include <stdint.h>

#define T_STEPS 200
#define BATCH   256
#define NS      256   // states S
#define NA      16    // actions A
#define DOBS    128
#define DCTL    16
#define LOG2PI  1.8378770664093453f
#define EPS_F   1e-6f

typedef float f32x4 __attribute__((ext_vector_type(4)));
typedef short s16x8 __attribute__((ext_vector_type(8)));
typedef short s16x4 __attribute__((ext_vector_type(4)));

static __device__ __forceinline__ unsigned short f2bf(float f) {
    union { float f; unsigned u; } v; v.f = f;
    unsigned u = v.u;
    u += 0x7fffu + ((u >> 16) & 1u);   // RNE
    return (unsigned short)(u >> 16);
}

// agent-coherent (Infinity-Cache-routed) relaxed load/store: no fences, no
// L2 writeback/invalidate. Correctness per LLVM gfx950 memory model.
static __device__ __forceinline__ float ld_agent(const float* p) {
    return __hip_atomic_load(p, __ATOMIC_RELAXED, __HIP_MEMORY_SCOPE_AGENT);
}
static __device__ __forceinline__ void st_agent(float* p, float v) {
    __hip_atomic_store(p, v, __ATOMIC_RELAXED, __HIP_MEMORY_SCOPE_AGENT);
}

// ---- prep: obs weights  W=(-0.5*iv || mu*iv) stored transposed [256 d'][256 s], C[s]
__global__ __launch_bounds__(128) void k_prep_obs(const float* __restrict__ obs_mu,
                                                  const float* __restrict__ obs_lv,
                                                  float* __restrict__ WT,
                                                  float* __restrict__ Cs) {
    int s = blockIdx.x, d = threadIdx.x;
    float lv = obs_lv[s * DOBS + d];
    float mu = obs_mu[s * DOBS + d];
    float iv = expf(-lv);
    WT[d * NS + s]          = -0.5f * iv;
    WT[(DOBS + d) * NS + s] = mu * iv;
    float part = mu * mu * iv + lv;
    for (int m = 1; m < 64; m <<= 1) part += __shfl_xor(part, m, 64);
    __shared__ float red[2];
    if ((threadIdx.x & 63) == 0) red[threadIdx.x >> 6] = part;
    __syncthreads();
    if (threadIdx.x == 0) Cs[s] = -0.5f * (red[0] + red[1] + DOBS * LOG2PI);
}

// ---- prep: ctl weights
__global__ __launch_bounds__(256) void k_prep_ctl(const float* __restrict__ cmu,
                                                  const float* __restrict__ clv,
                                                  float* __restrict__ cw1,
                                                  float* __restrict__ cw2,
                                                  float* __restrict__ cc) {
    int t = threadIdx.x;           // (a,d) pairs: a = t>>4, d = t&15
    int a = t >> 4, d = t & 15;
    float lv = clv[a * DCTL + d];
    float mu = cmu[a * DCTL + d];
    float iv = expf(-lv);
    cw1[t] = -0.5f * iv;
    cw2[t] = mu * iv;
    float part = mu * mu * iv + lv;
    for (int m = 1; m < 16; m <<= 1) part += __shfl_xor(part, m, 64);
    if (d == 0) cc[a] = -0.5f * (part + DCTL * LOG2PI);
}

// ---- prep: log_softmax(pi0)
__global__ __launch_bounds__(64) void k_prep_pi0(const float* __restrict__ pl,
                                                 float* __restrict__ lpi0) {
    int l = threadIdx.x;
    float v[4]; float m = -1e30f;
    for (int k = 0; k < 4; k++) { v[k] = pl[l + 64 * k]; m = fmaxf(m, v[k]); }
    for (int mm = 1; mm < 64; mm <<= 1) m = fmaxf(m, __shfl_xor(m, mm, 64));
    float ssum = 0.f;
    for (int k = 0; k < 4; k++) ssum += expf(v[k] - m);
    for (int mm = 1; mm < 64; mm <<= 1) ssum += __shfl_xor(ssum, mm, 64);
    float ls = logf(ssum);
    for (int k = 0; k < 4; k++) lpi0[l + 64 * k] = v[k] - m - ls;
}

// ---- prep: zero the sync flags (kernel-dispatch boundary makes them visible)
__global__ __launch_bounds__(512) void k_zero(int* __restrict__ f) {
    f[threadIdx.x] = 0;
}

// ---- prep: trans softmax, scattered into bf16 MFMA B-fragment layout.
__global__ __launch_bounds__(256) void k_trans(const float* __restrict__ tl,
                                               __hip_bfloat16* __restrict__ TRf) {
    int wave = threadIdx.x >> 6, lane = threadIdx.x & 63;
    int row = blockIdx.x * 4 + wave;        // (a,i) row in [0,4096)
    int a = row >> 8, i = row & 255;
    const float* src = tl + (size_t)row * NS;
    float v[4]; float m = -1e30f;
    for (int k = 0; k < 4; k++) { v[k] = src[lane + 64 * k]; m = fmaxf(m, v[k]); }
    for (int mm = 1; mm < 64; mm <<= 1) m = fmaxf(m, __shfl_xor(m, mm, 64));
    float ssum = 0.f; float ev[4];
    for (int k = 0; k < 4; k++) { ev[k] = expf(v[k] - m); ssum += ev[k]; }
    for (int mm = 1; mm < 64; mm <<= 1) ssum += __shfl_xor(ssum, mm, 64);
    float inv = 1.f / ssum;
    int kk = i >> 5;
    int lsub = ((i >> 3) & 3) * 16 + a;
    int e = i & 7;
    for (int k = 0; k < 4; k++) {
        int j = lane + 64 * k;
        float p = ev[k] * inv;
        TRf[((size_t)(j * 8 + kk) * 64 + lsub) * 8 + e] = __float2bfloat16(p);
    }
}

// ---- prep: act_prior into B-frag layout, split bf16 hi/lo for precision.
__global__ __launch_bounds__(64) void k_prep_ap(const float* __restrict__ ap,
                                                __hip_bfloat16* __restrict__ APh,
                                                __hip_bfloat16* __restrict__ APl) {
    int kk = blockIdx.x, lane = threadIdx.x;
    for (int e = 0; e < 8; e++) {
        int i = kk * 32 + (lane >> 4) * 8 + e;
        int a = lane & 15;
        float v = ap[i * NA + a];
        __hip_bfloat16 hb = __float2bfloat16(v);
        float hi = __bfloat162float(hb);
        APh[(kk * 64 + lane) * 8 + e] = hb;
        APl[(kk * 64 + lane) * 8 + e] = __float2bfloat16(v - hi);
    }
}

// ---- obs_lp for all (t,b): GEMM [51200,256]x[256,256] f32. Block = 32 rows.
__global__ __launch_bounds__(256) void k_obslp(const float* __restrict__ x,
                                               const float* __restrict__ WT,
                                               const float* __restrict__ Cs,
                                               float* __restrict__ obs) {
    __shared__ float f[32 * 256];
    int r0 = blockIdx.x * 32;
    for (int idx = threadIdx.x; idx < 32 * DOBS; idx += 256) {
        int r = idx >> 7, d = idx & 127;
        float v = x[(size_t)(r0 + r) * DOBS + d];
        f[r * 256 + d] = v * v;
        f[r * 256 + 128 + d] = v;
    }
    __syncthreads();
    int s = threadIdx.x;
    float acc[32];
#pragma unroll
    for (int r = 0; r < 32; r++) acc[r] = 0.f;
    for (int d4 = 0; d4 < 64; d4++) {
        float w0 = WT[(d4 * 4 + 0) * NS + s];
        float w1 = WT[(d4 * 4 + 1) * NS + s];
        float w2 = WT[(d4 * 4 + 2) * NS + s];
        float w3 = WT[(d4 * 4 + 3) * NS + s];
#pragma unroll
        for (int r = 0; r < 32; r++) {
            f32x4 fv = *reinterpret_cast<const f32x4*>(&f[r * 256 + d4 * 4]);
            acc[r] += fv.x * w0 + fv.y * w1 + fv.z * w2 + fv.w * w3;
        }
    }
    float c = Cs[s];
#pragma unroll
    for (int r = 0; r < 32; r++) obs[(size_t)(r0 + r) * NS + s] = acc[r] + c;
}

// ---- ctl_lp for all (s,b,a), s in [0,199)
__global__ __launch_bounds__(256) void k_ctllp(const float* __restrict__ u,
                                               const float* __restrict__ cw1,
                                               const float* __restrict__ cw2,
                                               const float* __restrict__ cc,
                                               float* __restrict__ ctl) {
    int idx = blockIdx.x * 256 + threadIdx.x;   // (r, a)
    int r = idx >> 4, a = idx & 15;
    const float* ur = u + (size_t)r * DCTL;
    const float* w1 = cw1 + a * DCTL;
    const float* w2 = cw2 + a * DCTL;
    float acc = cc[a];
#pragma unroll
    for (int d = 0; d < 16; d++) {
        float uv = ur[d];
        acc += uv * uv * w1[d] + uv * w2[d];
    }
    ctl[idx] = acc;
}

// ================= persistent scan kernel =================
// grid = 256 blocks (1/CU), 256 threads. 16 bt-groups x 16 jt.
// Cross-block exchange via agent-scope RELAXED atomics (Infinity-Cache routed);
// ordering via s_waitcnt vmcnt(0) before the flag add. NO fences in the loop.
struct ScanArgs {
    const float* obs;
    const float* ctlp;
    const float* lpi0;
    const __hip_bfloat16* TRf;
    const __hip_bfloat16* APh;
    const __hip_bfloat16* APl;
    float* lgA;
    float* lgB;
    float* out_ab;
    float* out_aa;
    int*   flags;     // one counter per bt, 32-int stride
};

__global__ __launch_bounds__(256, 1) void k_scan_p(ScanArgs A) {
    const int bid  = blockIdx.x;
    const int bt   = bid >> 4;
    const int jt   = bid & 15;
    const int tid  = threadIdx.x;
    const int wv   = tid >> 6, lane = tid & 63;
    const int kgrp = lane >> 4, arow = lane & 15;
    const int b0   = bt * 16;
    int* flag = A.flags + bt * 32;

    __shared__ short AFL[8][16][32];   // bf16 p in A-frag layout [kk][row][koff]

    // ---- preload constant fragments into registers (1 block/CU -> VGPRs free)
    s16x8 bfr[4][8];
#pragma unroll
    for (int q = 0; q < 4; q++) {
        int ct = jt * 16 + wv * 4 + q;
#pragma unroll
        for (int kk = 0; kk < 8; kk++)
            bfr[q][kk] = *((const s16x8*)A.TRf + (size_t)(ct * 8 + kk) * 64 + lane);
    }
    s16x8 aph[8], apl[8];
#pragma unroll
    for (int kk = 0; kk < 8; kk++) {
        aph[kk] = *((const s16x8*)A.APh + kk * 64 + lane);
        apl[kk] = *((const s16x8*)A.APl + kk * 64 + lane);
    }
    f32x4 lp0 = *(const f32x4*)&A.lpi0[lane * 4];

    for (int s = 0; s < T_STEPS - 1; s++) {
        const float* lin = (s & 1) ? A.lgB : A.lgA;   // R(s) = buf[s&1]
        float*       lout = (s & 1) ? A.lgA : A.lgB;  // W(s) = buf[(s+1)&1]

        // obs prefetch for time s+1 (consumed at end of phase 5) — in flight
        // across the wait below.
        float obs_pf[16];
#pragma unroll
        for (int q2 = 0; q2 < 4; q2++)
#pragma unroll
            for (int r = 0; r < 4; r++)
                obs_pf[q2 * 4 + r] =
                    A.obs[((size_t)(s + 1) * BATCH + b0 + kgrp * 4 + r) * NS + jt * 16 + wv * 4 + q2];

        // ---- wait for bt-group to finish step s-1 (relaxed poll, no fences)
        if (s > 0) {
            if (tid == 0) {
                int tgt = 16 * s;
                while (__hip_atomic_load(flag, __ATOMIC_RELAXED, __HIP_MEMORY_SCOPE_AGENT) < tgt)
                    __builtin_amdgcn_s_sleep(2);
            }
            __syncthreads();
        }

        // ---- phase 1: load logit rows (agent-coherent), softmax -> p
        float vr[4][4];
        if (s == 0) {
#pragma unroll
            for (int q = 0; q < 4; q++) {
                int bb = b0 + wv * 4 + q;
                f32x4 o = *(const f32x4*)&A.obs[(size_t)bb * NS + lane * 4];
                vr[q][0] = o.x + lp0.x; vr[q][1] = o.y + lp0.y;
                vr[q][2] = o.z + lp0.z; vr[q][3] = o.w + lp0.w;
            }
        } else {
#pragma unroll
            for (int q = 0; q < 4; q++) {
                const float* rp = &lin[(size_t)(b0 + wv * 4 + q) * NS + lane * 4];
#pragma unroll
                for (int k = 0; k < 4; k++) vr[q][k] = ld_agent(rp + k);
            }
        }
#pragma unroll
        for (int q = 0; q < 4; q++) {
            int r = wv * 4 + q, bb = b0 + r;
            float m = fmaxf(fmaxf(vr[q][0], vr[q][1]), fmaxf(vr[q][2], vr[q][3]));
            for (int mm = 1; mm < 64; mm <<= 1) m = fmaxf(m, __shfl_xor(m, mm, 64));
            float e0 = __expf(vr[q][0] - m), e1 = __expf(vr[q][1] - m);
            float e2 = __expf(vr[q][2] - m), e3 = __expf(vr[q][3] - m);
            float ss = (e0 + e1) + (e2 + e3);
            for (int mm = 1; mm < 64; mm <<= 1) ss += __shfl_xor(ss, mm, 64);
            float inv = 1.f / ss;
            float p0 = e0 * inv, p1 = e1 * inv, p2 = e2 * inv, p3 = e3 * inv;
            if ((lane >> 2) == jt) {
                f32x4 pv = {p0, p1, p2, p3};
                *(f32x4*)&A.out_ab[((size_t)s * BATCH + bb) * NS + lane * 4] = pv;
            }
            s16x4 sv;
            sv[0] = (short)f2bf(p0); sv[1] = (short)f2bf(p1);
            sv[2] = (short)f2bf(p2); sv[3] = (short)f2bf(p3);
            *(s16x4*)&AFL[lane >> 3][r][(lane & 7) * 4] = sv;   // kk=lane>>3, koff=(lane&7)*4
        }
        __syncthreads();

        // ---- A-fragments for this bt's 16 rows
        s16x8 afr[8];
#pragma unroll
        for (int kk = 0; kk < 8; kk++)
            afr[kk] = *(const s16x8*)&AFL[kk][arow][kgrp * 8];

        // ---- phase 3: g = p @ act_prior via MFMA (hi+lo), then a_t in-register.
        f32x4 g = {0.f, 0.f, 0.f, 0.f};
#pragma unroll
        for (int kk = 0; kk < 8; kk++)
            g = __builtin_amdgcn_mfma_f32_16x16x32_bf16(afr[kk], aph[kk], g, 0, 0, 0);
#pragma unroll
        for (int kk = 0; kk < 8; kk++)
            g = __builtin_amdgcn_mfma_f32_16x16x32_bf16(afr[kk], apl[kk], g, 0, 0, 0);

        float at[4];
#pragma unroll
        for (int q = 0; q < 4; q++) {
            float gv = g[q];
            float m = gv;
            for (int mm = 1; mm < 16; mm <<= 1) m = fmaxf(m, __shfl_xor(m, mm, 64));
            float e1 = __expf(gv - m);
            float s1 = e1;
            for (int mm = 1; mm < 16; mm <<= 1) s1 += __shfl_xor(s1, mm, 64);
            float apr = e1 / s1;
            float al = A.ctlp[((size_t)s * BATCH + b0 + kgrp * 4 + q) * NA + arow]
                       + __logf(apr + EPS_F);
            float m2 = al;
            for (int mm = 1; mm < 16; mm <<= 1) m2 = fmaxf(m2, __shfl_xor(m2, mm, 64));
            float e2 = __expf(al - m2);
            float s2 = e2;
            for (int mm = 1; mm < 16; mm <<= 1) s2 += __shfl_xor(s2, mm, 64);
            at[q] = e2 / s2;
            if (jt == 0)
                A.out_aa[((size_t)s * BATCH + b0 + kgrp * 4 + q) * NA + arow] = at[q];
        }

        // ---- phase 5: m2 = p @ trans (per col-tile), contract a_t, write logits
#pragma unroll
        for (int q2 = 0; q2 < 4; q2++) {
            int ct = jt * 16 + wv * 4 + q2;
            f32x4 acc = {0.f, 0.f, 0.f, 0.f};
#pragma unroll
            for (int kk = 0; kk < 8; kk++)
                acc = __builtin_amdgcn_mfma_f32_16x16x32_bf16(afr[kk], bfr[q2][kk], acc, 0, 0, 0);
#pragma unroll
            for (int r = 0; r < 4; r++) {
                float vv = acc[r] * at[r];
                for (int mm = 1; mm < 16; mm <<= 1) vv += __shfl_xor(vv, mm, 64);
                if (arow == 0) {
                    float lz = __logf(vv + NS * EPS_F);
                    st_agent(&lout[(size_t)(b0 + kgrp * 4 + r) * NS + ct],
                             obs_pf[q2 * 4 + r] + lz);
                }
            }
        }

        // ---- signal: drain own agent-stores to coherence point, then add.
        asm volatile("s_waitcnt vmcnt(0)" ::: "memory");
        __syncthreads();
        if (tid == 0)
            __hip_atomic_fetch_add(flag, 1, __ATOMIC_RELAXED, __HIP_MEMORY_SCOPE_AGENT);
    }

    // ---- epilogue: softmax of final beliefs -> alpha_b[T-1]
    if (tid == 0) {
        int tgt = 16 * (T_STEPS - 1);
        while (__hip_atomic_load(flag, __ATOMIC_RELAXED, __HIP_MEMORY_SCOPE_AGENT) < tgt)
            __builtin_amdgcn_s_sleep(2);
    }
    __syncthreads();
    const float* lin = ((T_STEPS - 1) & 1) ? A.lgB : A.lgA;
#pragma unroll
    for (int q = 0; q < 4; q++) {
        int r = wv * 4 + q, bb = b0 + r;
        float v0 = ld_agent(&lin[(size_t)bb * NS + lane * 4 + 0]);
        float v1 = ld_agent(&lin[(size_t)bb * NS + lane * 4 + 1]);
        float v2 = ld_agent(&lin[(size_t)bb * NS + lane * 4 + 2]);
        float v3 = ld_agent(&lin[(size_t)bb * NS + lane * 4 + 3]);
        float m = fmaxf(fmaxf(v0, v1), fmaxf(v2, v3));
        for (int mm = 1; mm < 64; mm <<= 1) m = fmaxf(m, __shfl_xor(m, mm, 64));
        float e0 = __expf(v0 - m), e1 = __expf(v1 - m);
        float e2 = __expf(v2 - m), e3 = __expf(v3 - m);
        float ss = (e0 + e1) + (e2 + e3);
        for (int mm = 1; mm < 64; mm <<= 1) ss += __shfl_xor(ss, mm, 64);
        float inv = 1.f / ss;
        if ((lane >> 2) == jt) {
            f32x4 pv = {e0 * inv, e1 * inv, e2 * inv, e3 * inv};
            *(f32x4*)&A.out_ab[((size_t)(T_STEPS - 1) * BATCH + bb) * NS + lane * 4] = pv;
        }
    }
}

extern "C" void kernel_launch(void* const* d_in, const int* in_sizes, int n_in,
                              void* d_out, int out_size, void* d_ws, size_t ws_size,
                              hipStream_t stream) {
    const float* x            = (const float*)d_in[0];
    const float* u            = (const float*)d_in[1];
    const float* obs_mu       = (const float*)d_in[2];
    const float* obs_lv       = (const float*)d_in[3];
    const float* ctl_mu       = (const float*)d_in[4];
    const float* ctl_lv       = (const float*)d_in[5];
    const float* trans_logits = (const float*)d_in[6];
    const float* pi0_logits   = (const float*)d_in[7];
    const float* act_prior    = (const float*)d_in[8];

    float* out_ab = (float*)d_out;
    float* out_aa = out_ab + (size_t)T_STEPS * BATCH * NS;

    char* w = (char*)d_ws;
    size_t off = 0;
    auto alloc = [&](size_t bytes) -> void* {
        void* pp = w + off;
        off += (bytes + 255) & ~(size_t)255;
        return pp;
    };
    float* WT   = (float*)alloc((size_t)256 * 256 * 4);
    float* Cs   = (float*)alloc(256 * 4);
    float* cw1  = (float*)alloc(256 * 4);
    float* cw2  = (float*)alloc(256 * 4);
    float* cc   = (float*)alloc(16 * 4);
    float* lpi0 = (float*)alloc(256 * 4);
    __hip_bfloat16* TRf = (__hip_bfloat16*)alloc((size_t)4096 * 256 * 2);
    __hip_bfloat16* APh = (__hip_bfloat16*)alloc((size_t)8 * 64 * 8 * 2);
    __hip_bfloat16* APl = (__hip_bfloat16*)alloc((size_t)8 * 64 * 8 * 2);
    float* obs  = (float*)alloc((size_t)T_STEPS * BATCH * NS * 4);
    float* ctlp = (float*)alloc((size_t)(T_STEPS - 1) * BATCH * NA * 4);
    float* lgA  = (float*)alloc((size_t)BATCH * NS * 4);
    float* lgB  = (float*)alloc((size_t)BATCH * NS * 4);
    int*   flags = (int*)alloc(16 * 32 * 4);
    if (off > ws_size) return;   // insufficient scratch -> fail loudly

    k_zero<<<1, 512, 0, stream>>>(flags);
    k_prep_obs<<<256, 128, 0, stream>>>(obs_mu, obs_lv, WT, Cs);
    k_prep_ctl<<<1, 256, 0, stream>>>(ctl_mu, ctl_lv, cw1, cw2, cc);
    k_prep_pi0<<<1, 64, 0, stream>>>(pi0_logits, lpi0);
    k_trans<<<1024, 256, 0, stream>>>(trans_logits, TRf);
    k_prep_ap<<<8, 64, 0, stream>>>(act_prior, APh, APl);
    k_obslp<<<1600, 256, 0, stream>>>(x, WT, Cs, obs);
    k_ctllp<<<3184, 256, 0, stream>>>(u, cw1, cw2, cc, ctlp);

    ScanArgs args;
    args.obs = obs; args.ctlp = ctlp; args.lpi0 = lpi0;
    args.TRf = TRf; args.APh = APh; args.APl = APl;
    args.lgA = lgA; args.lgB = lgB;
    args.out_ab = out_ab; args.out_aa = out_aa; args.flags = flags;
    k_scan_p<<<256, 256, 0, stream>>>(args);
}